// Round 8
// baseline (201.383 us; speedup 1.0000x reference)
//
#include <hip/hip_runtime.h>
#include <stdint.h>

#define CHS 589824           // W*H*Z
#define ROWS 18432           // B*W*H
#define WHn 9216             // W*H
#define NRED 1179648.0f      // B*W*H*Z

typedef short s16x8 __attribute__((ext_vector_type(8)));
typedef float f32x4v __attribute__((ext_vector_type(4)));

#define MFMA16 __builtin_amdgcn_mfma_f32_16x16x32_bf16

// ws layout (bytes): [0,10240) weight frags ; then part/part2/sc (f32)
#define WSFRAG 10240

// LDS regions (one block = one (b,w,h) row)
#define OXH 0        // X bf16 [z=64][ hi c:32 (64B) | lo c:32 (64B) ] stride 136 (8704)
#define OT  8704     // T_hi bf16 [z=64][o:36] stride 72 (4608)
#define OTL 13312    // T_lo bf16 [z=64][o:36] stride 72 (4608)
#define OP  17920    // P_hi bf16 [y=64][o:36] stride 72 (4608)
#define OG  22528    // G bf16 [c=32][y:72] stride 144  (4608)
#define LDSZ 27136   // x6 = 162816 <= 160 KiB -> 6 blocks/CU
// overlays:
#define OA  OT       // A' bf16 [z=64][y:72] stride 144 (9216 == OT+OTL region), after B3
#define ORT OP       // Rt bf16 [z=64][c:36] stride 72  (4608), after B3
#define OO  OT       // Ot f32  [z=64][o:33] stride 132 (8448 <= 9216), after B3b

static __device__ __forceinline__ uint16_t bfh(float v) {
    union { __bf16 h; uint16_t u; } c; c.h = (__bf16)v; return c.u;
}
static __device__ __forceinline__ float bf2f(uint16_t u) {
    union { uint32_t x; float f; } c; c.x = (uint32_t)u << 16; return c.f;
}
static __device__ __forceinline__ uint32_t pk2u(uint16_t a, uint16_t b) {
    return (uint32_t)a | ((uint32_t)b << 16);
}
static __device__ __forceinline__ uint32_t pkbf(float a, float b) {
    return pk2u(bfh(a), bfh(b));
}
// 16B from 8B-aligned LDS as two b64s (rows with stride 72/136 are 8-aligned only)
static __device__ __forceinline__ s16x8 rd8(const char* p) {
    union { uint64_t q[2]; s16x8 s; } v;
    v.q[0] = *(const uint64_t*)p;
    v.q[1] = *(const uint64_t*)(p + 8);
    return v.s;
}

// hi+lo A-frags of a row-major [16*2][32] f32 weight matrix.
static __device__ __forceinline__ void wfrag2(const float* __restrict__ Wp, int mt, int l15, int kb,
                                              s16x8& hi, s16x8& lo) {
    const float* p = Wp + (l15 + 16*mt)*32 + 8*kb;
    const float4 f0 = *(const float4*)p;
    const float4 f1 = *(const float4*)(p + 4);
    float f[8] = {f0.x, f0.y, f0.z, f0.w, f1.x, f1.y, f1.z, f1.w};
    union { uint32_t u[4]; s16x8 v; } rh, rl;
    #pragma unroll
    for (int i = 0; i < 4; ++i) {
        const uint16_t h0 = bfh(f[2*i]), h1 = bfh(f[2*i+1]);
        rh.u[i] = pk2u(h0, h1);
        rl.u[i] = pk2u(bfh(f[2*i] - bf2f(h0)), bfh(f[2*i+1] - bf2f(h1)));
    }
    hi = rh.v; lo = rl.v;
}
static __device__ __forceinline__ s16x8 wfragh(const float* __restrict__ Wp, int mt, int l15, int kb) {
    const float* p = Wp + (l15 + 16*mt)*32 + 8*kb;
    const float4 f0 = *(const float4*)p;
    const float4 f1 = *(const float4*)(p + 4);
    union { uint32_t u[4]; s16x8 v; } r;
    r.u[0] = pkbf(f0.x, f0.y); r.u[1] = pkbf(f0.z, f0.w);
    r.u[2] = pkbf(f1.x, f1.y); r.u[3] = pkbf(f1.z, f1.w);
    return r.v;
}

// k0: one block, precompute weight fragments into ws
__global__ __launch_bounds__(256) void k0_frag(
    const float* __restrict__ theta_w, const float* __restrict__ phi_w,
    const float* __restrict__ Ww, char* __restrict__ ws)
{
    const int tid = threadIdx.x;
    const int m = tid >> 7;            // 0 = theta, 1 = phi
    const int r = tid & 127;
    const int mt = r >> 6, l = r & 63;
    s16x8 hi, lo;
    wfrag2(m ? phi_w : theta_w, mt, l & 15, l >> 4, hi, lo);
    *(s16x8*)(ws + m*4096 + (mt*64 + l)*16)        = hi;
    *(s16x8*)(ws + m*4096 + 2048 + (mt*64 + l)*16) = lo;
    if (tid < 128) {
        const int mtw = tid >> 6, lw = tid & 63;
        *(s16x8*)(ws + 8192 + (mtw*64 + lw)*16) = wfragh(Ww, mtw, lw & 15, lw >> 4);
    }
}

__global__ __launch_bounds__(256, 6) void k1_row(
    const float* __restrict__ x, const float* __restrict__ spacings,
    const float* __restrict__ theta_b, const float* __restrict__ phi_b,
    const float* __restrict__ g_w, const float* __restrict__ g_b,
    const float* __restrict__ Wb, const char* __restrict__ frags,
    float* __restrict__ out, float* __restrict__ part)
{
    __shared__ __align__(16) char lds[LDSZ];
    const int t = threadIdx.x;
    const int wv = t >> 6, l = t & 63;
    const int l15 = l & 15, kb = l >> 4;
    const int row = blockIdx.x;
    const int b = row / WHn, wh = row - b*WHn;
    const long base = (long)b*32*CHS + (long)wh*64;
    const int zr = 16*wv + l15;

    // ===== phase 0: load x col z=l (8 channels), write X hi|lo planes, G via shfl =====
    float xv[8];
    #pragma unroll
    for (int j = 0; j < 8; ++j) xv[j] = x[base + (long)(8*wv + j)*CHS + l];
    #pragma unroll
    for (int j = 0; j < 4; ++j) {
        const uint16_t h0 = bfh(xv[2*j]), h1 = bfh(xv[2*j+1]);
        *(uint32_t*)(lds + OXH + l*136 + (8*wv + 2*j)*2)      = pk2u(h0, h1);
        *(uint32_t*)(lds + OXH + l*136 + 64 + (8*wv + 2*j)*2) =
            pk2u(bfh(xv[2*j] - bf2f(h0)), bfh(xv[2*j+1] - bf2f(h1)));
    }
    #pragma unroll
    for (int j = 0; j < 8; ++j) {
        const int c = 8*wv + j;
        float xm = __shfl_up(xv[j], 1);   if (l == 0)  xm = 0.f;
        float xp = __shfl_down(xv[j], 1); if (l == 63) xp = 0.f;
        const float g = g_w[3*c]*xm + g_w[3*c+1]*xv[j] + g_w[3*c+2]*xp + g_b[c];
        *(uint16_t*)(lds + OG + c*144 + 2*l) = bfh(g);
    }
    __syncthreads();   // B1

    // ===== phase 1: T = Th*X+tb (waves 0,1) / P = Ph*X+pb (waves 2,3) =====
    {
        const char* fb = frags + ((wv < 2) ? 0 : 4096);
        const float* wbp = (wv < 2) ? theta_b : phi_b;
        const int    dst = (wv < 2) ? OT : OP;
        const bool   doLo = (wv < 2);
        const int    ntb = (wv & 1) * 2;
        const s16x8 a0h = *(const s16x8*)(fb + l*16);
        const s16x8 a1h = *(const s16x8*)(fb + 1024 + l*16);
        const s16x8 a0l = *(const s16x8*)(fb + 2048 + l*16);
        const s16x8 a1l = *(const s16x8*)(fb + 3072 + l*16);
        const float4 b0 = *(const float4*)(wbp + 4*kb);
        const float4 b1 = *(const float4*)(wbp + 16 + 4*kb);
        #pragma unroll
        for (int n2 = 0; n2 < 2; ++n2) {
            const int z = 16*(ntb + n2) + l15;
            const s16x8 bxh = rd8(lds + OXH + z*136 + 16*kb);
            const s16x8 bxl = rd8(lds + OXH + z*136 + 64 + 16*kb);
            f32x4v a0; a0[0]=b0.x; a0[1]=b0.y; a0[2]=b0.z; a0[3]=b0.w;
            f32x4v a1; a1[0]=b1.x; a1[1]=b1.y; a1[2]=b1.z; a1[3]=b1.w;
            a0 = MFMA16(a0h, bxh, a0, 0, 0, 0);
            a0 = MFMA16(a0h, bxl, a0, 0, 0, 0);
            a0 = MFMA16(a0l, bxh, a0, 0, 0, 0);
            a1 = MFMA16(a1h, bxh, a1, 0, 0, 0);
            a1 = MFMA16(a1h, bxl, a1, 0, 0, 0);
            a1 = MFMA16(a1l, bxh, a1, 0, 0, 0);
            // transposed store: dst[z][o], o = 16*mt+4*kb+r
            uint16_t h[8];
            #pragma unroll
            for (int r = 0; r < 4; ++r) { h[r] = bfh(a0[r]); h[4+r] = bfh(a1[r]); }
            union { uint32_t u[2]; uint64_t q; } w0, w1;
            w0.u[0] = pk2u(h[0], h[1]); w0.u[1] = pk2u(h[2], h[3]);
            w1.u[0] = pk2u(h[4], h[5]); w1.u[1] = pk2u(h[6], h[7]);
            *(uint64_t*)(lds + dst + z*72 + 8*kb)      = w0.q;
            *(uint64_t*)(lds + dst + z*72 + 32 + 8*kb) = w1.q;
            if (doLo) {
                union { uint32_t u[2]; uint64_t q; } v0, v1;
                v0.u[0] = pkbf(a0[0]-bf2f(h[0]), a0[1]-bf2f(h[1]));
                v0.u[1] = pkbf(a0[2]-bf2f(h[2]), a0[3]-bf2f(h[3]));
                v1.u[0] = pkbf(a1[0]-bf2f(h[4]), a1[1]-bf2f(h[5]));
                v1.u[1] = pkbf(a1[2]-bf2f(h[6]), a1[3]-bf2f(h[7]));
                *(uint64_t*)(lds + OTL + z*72 + 8*kb)      = v0.q;
                *(uint64_t*)(lds + OTL + z*72 + 32 + 8*kb) = v1.q;
            }
        }
    }
    __syncthreads();   // B2

    // ===== phase 2a: F' = P_hi^T * (T_hi + T_lo) -> Fq regs =====
    f32x4v Fq[4];
    {
        const s16x8 bth = rd8(lds + OT  + zr*72 + 16*kb);
        const s16x8 btl = rd8(lds + OTL + zr*72 + 16*kb);
        #pragma unroll
        for (int yt = 0; yt < 4; ++yt) {
            const int y = 16*yt + l15;
            const s16x8 pah = rd8(lds + OP + y*72 + 16*kb);
            f32x4v zz; zz[0]=0.f; zz[1]=0.f; zz[2]=0.f; zz[3]=0.f;
            zz = MFMA16(pah, bth, zz, 0, 0, 0);
            zz = MFMA16(pah, btl, zz, 0, 0, 0);
            Fq[yt] = zz;   // F'[y=16yt+4kb+r][z=zr]
        }
    }
    __syncthreads();   // B3 (T/P reads done -> A'/Rt overlays legal)

    // ===== phase 2b: softmax over y, A' -> OA (stride 144, 16-aligned rows) =====
    {
        float mx = -3.4e38f;
        #pragma unroll
        for (int yt = 0; yt < 4; ++yt)
            #pragma unroll
            for (int r = 0; r < 4; ++r) mx = fmaxf(mx, Fq[yt][r]);
        mx = fmaxf(mx, __shfl_xor(mx, 16));
        mx = fmaxf(mx, __shfl_xor(mx, 32));
        float p[4][4]; float sum = 0.f;
        #pragma unroll
        for (int yt = 0; yt < 4; ++yt)
            #pragma unroll
            for (int r = 0; r < 4; ++r) { p[yt][r] = __expf(Fq[yt][r] - mx); sum += p[yt][r]; }
        sum += __shfl_xor(sum, 16);
        sum += __shfl_xor(sum, 32);
        const float inv = 1.0f / sum;
        #pragma unroll
        for (int yt = 0; yt < 4; ++yt) {
            *(uint32_t*)(lds + OA + zr*144 + (16*yt + 4*kb)*2)     = pkbf(p[yt][0]*inv, p[yt][1]*inv);
            *(uint32_t*)(lds + OA + zr*144 + (16*yt + 4*kb)*2 + 4) = pkbf(p[yt][2]*inv, p[yt][3]*inv);
        }
    }

    // ===== phase 3: Y = G * A'^T, residual(+mask) from X-hi, Rt -> ORT =====
    {
        f32x4v Yq[2];
        #pragma unroll
        for (int r = 0; r < 4; ++r) { Yq[0][r] = 0.f; Yq[1][r] = 0.f; }
        #pragma unroll
        for (int ks = 0; ks < 2; ++ks) {
            const s16x8 bA = *(const s16x8*)(lds + OA + zr*144 + 64*ks + 16*kb);
            #pragma unroll
            for (int mt = 0; mt < 2; ++mt) {
                const s16x8 gA = *(const s16x8*)(lds + OG + (16*mt + l15)*144 + 64*ks + 16*kb);
                Yq[mt] = MFMA16(gA, bA, Yq[mt], 0, 0, 0);
            }
        }
        const bool msk = spacings[b*3 + 2] <= 1.5f;
        #pragma unroll
        for (int mt = 0; mt < 2; ++mt) {
            const uint64_t xh = *(const uint64_t*)(lds + OXH + zr*136 + (16*mt + 4*kb)*2);
            float rv[4];
            #pragma unroll
            for (int r = 0; r < 4; ++r) {
                const float xr = bf2f((uint16_t)(xh >> (16*r)));
                rv[r] = msk ? (Yq[mt][r] + xr) : xr;
            }
            union { uint32_t u[2]; uint64_t q; } w;
            w.u[0] = pkbf(rv[0], rv[1]); w.u[1] = pkbf(rv[2], rv[3]);
            *(uint64_t*)(lds + ORT + zr*72 + 32*mt + 8*kb) = w.q;
        }
    }
    __syncthreads();   // B3b (A' reads done -> Ot may overlay OA region)

    // ===== phase 4: O = W * R + wb -> Ot f32 [z][33] stride 132 =====
    {
        const s16x8 bR = rd8(lds + ORT + zr*72 + 16*kb);
        #pragma unroll
        for (int mt = 0; mt < 2; ++mt) {
            const s16x8 aW = *(const s16x8*)(frags + 8192 + (mt*64 + l)*16);
            const float4 wb4 = *(const float4*)(Wb + 16*mt + 4*kb);
            f32x4v acc; acc[0]=wb4.x; acc[1]=wb4.y; acc[2]=wb4.z; acc[3]=wb4.w;
            acc = MFMA16(aW, bR, acc, 0, 0, 0);
            #pragma unroll
            for (int r = 0; r < 4; ++r)
                *(float*)(lds + OO + zr*132 + (16*mt + 4*kb + r)*4) = acc[r];
        }
    }
    __syncthreads();   // B4

    // ===== phase 5: coalesced store + BN partials (butterfly) =====
    #pragma unroll
    for (int k = 0; k < 8; ++k) {
        const int o = wv + 4*k;
        const float v = *(const float*)(lds + OO + l*132 + o*4);
        out[base + (long)o*CHS + l] = v;
        float s1 = v, s2 = v*v;
        #pragma unroll
        for (int off = 32; off >= 1; off >>= 1) {
            s1 += __shfl_xor(s1, off);
            s2 += __shfl_xor(s2, off);
        }
        if (l == 0) {
            part[row*64 + o]      = s1;
            part[row*64 + 32 + o] = s2;
        }
    }
}

// stage 2a: 256 blocks reduce 72 rows each
__global__ __launch_bounds__(256) void k2a(const float* __restrict__ part,
                                           float* __restrict__ part2)
{
    __shared__ float red[4][64];
    const int t = threadIdx.x, lane = t & 63, grp = t >> 6;
    const int p = blockIdx.x;
    float s = 0.f;
    for (int k = 0; k < 18; ++k) s += part[(p*72 + grp + 4*k)*64 + lane];
    red[grp][lane] = s;
    __syncthreads();
    if (t < 64) part2[p*64 + t] = red[0][t] + red[1][t] + red[2][t] + red[3][t];
}

// stage 2b: final reduce + BN scale/shift
__global__ __launch_bounds__(256) void k2b(const float* __restrict__ part2,
    const float* __restrict__ gamma, const float* __restrict__ beta,
    float* __restrict__ sc)
{
    __shared__ float red[4][64];
    __shared__ float tot[64];
    const int t = threadIdx.x, lane = t & 63, grp = t >> 6;
    float s = 0.f;
    for (int k = 0; k < 64; ++k) s += part2[(grp + 4*k)*64 + lane];
    red[grp][lane] = s;
    __syncthreads();
    if (t < 64) tot[t] = red[0][t] + red[1][t] + red[2][t] + red[3][t];
    __syncthreads();
    if (t < 32) {
        const float mean = tot[t] / NRED;
        const float var  = tot[32+t] / NRED - mean*mean;
        const float rstd = rsqrtf(var + 1e-5f);
        const float scale = gamma[t] * rstd;
        sc[t]    = scale;
        sc[32+t] = fmaf(-mean, scale, beta[t]);
    }
}

// stage 3: in-place affine normalize of d_out
__global__ __launch_bounds__(256) void k3_norm(float* __restrict__ out,
                                               const float* __restrict__ sc)
{
    __shared__ float s[64];
    if (threadIdx.x < 64) s[threadIdx.x] = sc[threadIdx.x];
    __syncthreads();
    const int total4 = 2*32*CHS/4;
    const int Q = CHS/4;
    for (int i = blockIdx.x*256 + threadIdx.x; i < total4; i += gridDim.x*256) {
        float4 v = ((const float4*)out)[i];
        const int c = (i / Q) & 31;
        const float scale = s[c], shift = s[32+c];
        v.x = fmaf(v.x, scale, shift);
        v.y = fmaf(v.y, scale, shift);
        v.z = fmaf(v.z, scale, shift);
        v.w = fmaf(v.w, scale, shift);
        ((float4*)out)[i] = v;
    }
}

extern "C" void kernel_launch(void* const* d_in, const int* in_sizes, int n_in,
                              void* d_out, int out_size, void* d_ws, size_t ws_size,
                              hipStream_t stream) {
    const float* x        = (const float*)d_in[0];
    const float* spacings = (const float*)d_in[1];
    const float* theta_w  = (const float*)d_in[2];
    const float* theta_b  = (const float*)d_in[3];
    const float* phi_w    = (const float*)d_in[4];
    const float* phi_b    = (const float*)d_in[5];
    const float* g_w      = (const float*)d_in[6];
    const float* g_b      = (const float*)d_in[7];
    const float* Ww       = (const float*)d_in[8];
    const float* Wb       = (const float*)d_in[9];
    const float* gamma    = (const float*)d_in[10];
    const float* beta     = (const float*)d_in[11];
    float* out   = (float*)d_out;
    char*  frags = (char*)d_ws;                         // WSFRAG bytes
    float* part  = (float*)((char*)d_ws + WSFRAG);      // ROWS*64 floats
    float* part2 = part + ROWS*64;                      // 256*64 floats
    float* sc    = part2 + 256*64;                      // 64 floats

    hipLaunchKernelGGL(k0_frag, dim3(1), dim3(256), 0, stream, theta_w, phi_w, Ww, frags);
    hipLaunchKernelGGL(k1_row, dim3(ROWS), dim3(256), 0, stream,
                       x, spacings, theta_b, phi_b, g_w, g_b, Wb, frags, out, part);
    hipLaunchKernelGGL(k2a, dim3(256), dim3(256), 0, stream, part, part2);
    hipLaunchKernelGGL(k2b, dim3(1), dim3(256), 0, stream, part2, gamma, beta, sc);
    hipLaunchKernelGGL(k3_norm, dim3(4096), dim3(256), 0, stream, out, sc);
}

// Round 9
// 194.681 us; speedup vs baseline: 1.0344x; 1.0344x over previous
//
#include <hip/hip_runtime.h>
#include <stdint.h>

#define CHS 589824           // W*H*Z
#define ROWS 18432           // B*W*H
#define WHn 9216             // W*H
#define NRED 1179648.0f      // B*W*H*Z

typedef short s16x8 __attribute__((ext_vector_type(8)));
typedef float f32x4v __attribute__((ext_vector_type(4)));

#define MFMA16 __builtin_amdgcn_mfma_f32_16x16x32_bf16

// ws layout (bytes): [0,10240) weight frags ; then part/part2/sc (f32)
//   frags: thetaH 0, thetaL 2048, phiH 4096, phiL 6144, W 8192 (c-permuted)
#define WSFRAG 10240

// LDS regions (one block = one (b,w,h) row)
#define OXH 0        // X bf16 [z=64][ hi c:32 (64B) | lo c:32 (64B) ] stride 136 (8704)
#define OP  8704     // P_hi bf16 [y=64][p:36] stride 72 (4608)  p = 8kb+4mt+r slot order
#define OG  13312    // G bf16 [c=32][p_G:68] stride 136 (4352)  p_G = y-permuted slot order
#define LDSZ 17664   // 8 blocks/CU (wave-slot capped)
// overlay after B3:
#define OO  OP       // Ot f32 [z=64][o:33] stride 132 (8448 <= 4608+4352=8960)

static __device__ __forceinline__ uint16_t bfh(float v) {
    union { __bf16 h; uint16_t u; } c; c.h = (__bf16)v; return c.u;
}
static __device__ __forceinline__ float bf2f(uint16_t u) {
    union { uint32_t x; float f; } c; c.x = (uint32_t)u << 16; return c.f;
}
static __device__ __forceinline__ uint32_t pk2u(uint16_t a, uint16_t b) {
    return (uint32_t)a | ((uint32_t)b << 16);
}
static __device__ __forceinline__ uint32_t pkbf(float a, float b) {
    return pk2u(bfh(a), bfh(b));
}
// 16B from 8B-aligned LDS as two b64s
static __device__ __forceinline__ s16x8 rd8(const char* p) {
    union { uint64_t q[2]; s16x8 s; } v;
    v.q[0] = *(const uint64_t*)p;
    v.q[1] = *(const uint64_t*)(p + 8);
    return v.s;
}

// identity-k hi+lo A-frags of row-major [32][32] f32 weights (for theta/phi vs X)
static __device__ __forceinline__ void wfrag2(const float* __restrict__ Wp, int mt, int l15, int kb,
                                              s16x8& hi, s16x8& lo) {
    const float* p = Wp + (l15 + 16*mt)*32 + 8*kb;
    const float4 f0 = *(const float4*)p;
    const float4 f1 = *(const float4*)(p + 4);
    float f[8] = {f0.x, f0.y, f0.z, f0.w, f1.x, f1.y, f1.z, f1.w};
    union { uint32_t u[4]; s16x8 v; } rh, rl;
    #pragma unroll
    for (int i = 0; i < 4; ++i) {
        const uint16_t h0 = bfh(f[2*i]), h1 = bfh(f[2*i+1]);
        rh.u[i] = pk2u(h0, h1);
        rl.u[i] = pk2u(bfh(f[2*i] - bf2f(h0)), bfh(f[2*i+1] - bf2f(h1)));
    }
    hi = rh.v; lo = rl.v;
}
// c-permuted A-frag for W (slot j <-> c = 16*(j>>2) + 4*kb + (j&3))
static __device__ __forceinline__ s16x8 wfragW(const float* __restrict__ Wp, int mt, int l15, int kb) {
    const float* p = Wp + (l15 + 16*mt)*32;
    const float4 f0 = *(const float4*)(p + 4*kb);
    const float4 f1 = *(const float4*)(p + 16 + 4*kb);
    union { uint32_t u[4]; s16x8 v; } r;
    r.u[0] = pkbf(f0.x, f0.y); r.u[1] = pkbf(f0.z, f0.w);
    r.u[2] = pkbf(f1.x, f1.y); r.u[3] = pkbf(f1.z, f1.w);
    return r.v;
}

// k0: one block, precompute weight fragments into ws
__global__ __launch_bounds__(256) void k0_frag(
    const float* __restrict__ theta_w, const float* __restrict__ phi_w,
    const float* __restrict__ Ww, char* __restrict__ ws)
{
    const int tid = threadIdx.x;
    const int m = tid >> 7;            // 0 = theta, 1 = phi
    const int r = tid & 127;
    const int mt = r >> 6, l = r & 63;
    s16x8 hi, lo;
    wfrag2(m ? phi_w : theta_w, mt, l & 15, l >> 4, hi, lo);
    *(s16x8*)(ws + m*4096 + (mt*64 + l)*16)        = hi;
    *(s16x8*)(ws + m*4096 + 2048 + (mt*64 + l)*16) = lo;
    if (tid < 128) {
        const int mtw = tid >> 6, lw = tid & 63;
        *(s16x8*)(ws + 8192 + (mtw*64 + lw)*16) = wfragW(Ww, mtw, lw & 15, lw >> 4);
    }
}

__global__ __launch_bounds__(256, 8) void k1_row(
    const float* __restrict__ x, const float* __restrict__ spacings,
    const float* __restrict__ theta_b, const float* __restrict__ phi_b,
    const float* __restrict__ g_w, const float* __restrict__ g_b,
    const float* __restrict__ Wb, const char* __restrict__ frags,
    float* __restrict__ out, float* __restrict__ part)
{
    __shared__ __align__(16) char lds[LDSZ];
    const int t = threadIdx.x;
    const int wv = t >> 6, l = t & 63;
    const int l15 = l & 15, kb = l >> 4;
    const int row = blockIdx.x;
    const int b = row / WHn, wh = row - b*WHn;
    const long base = (long)b*32*CHS + (long)wh*64;
    const int zr = 16*wv + l15;   // this wave's z (= y) tile column

    // ===== phase 0: load x col z=l (8 channels), write X hi|lo planes, G via shfl =====
    float xv[8];
    #pragma unroll
    for (int j = 0; j < 8; ++j) xv[j] = x[base + (long)(8*wv + j)*CHS + l];
    #pragma unroll
    for (int j = 0; j < 4; ++j) {
        const uint16_t h0 = bfh(xv[2*j]), h1 = bfh(xv[2*j+1]);
        *(uint32_t*)(lds + OXH + l*136 + (8*wv + 2*j)*2)      = pk2u(h0, h1);
        *(uint32_t*)(lds + OXH + l*136 + 64 + (8*wv + 2*j)*2) =
            pk2u(bfh(xv[2*j] - bf2f(h0)), bfh(xv[2*j+1] - bf2f(h1)));
    }
    // G store position: p_G(y=l) = 32*(l>>5) + 8*((l>>2)&3) + 4*((l>>4)&1) + (l&3)
    const int pG = 32*(l >> 5) + 8*((l >> 2) & 3) + 4*((l >> 4) & 1) + (l & 3);
    #pragma unroll
    for (int j = 0; j < 8; ++j) {
        const int c = 8*wv + j;
        float xm = __shfl_up(xv[j], 1);   if (l == 0)  xm = 0.f;
        float xp = __shfl_down(xv[j], 1); if (l == 63) xp = 0.f;
        const float g = g_w[3*c]*xm + g_w[3*c+1]*xv[j] + g_w[3*c+2]*xp + g_b[c];
        *(uint16_t*)(lds + OG + c*136 + 2*pG) = bfh(g);
    }
    __syncthreads();   // B1

    // ===== phase 1: own z-tile T (kept in regs) and P (hi -> LDS) =====
    s16x8 bth, btl;   // T as F'-B-frags (slot j = 4*mt + r), hi+lo
    {
        const s16x8 bxh = rd8(lds + OXH + zr*136 + 16*kb);
        const s16x8 bxl = rd8(lds + OXH + zr*136 + 64 + 16*kb);
        // T = theta*X + tb (split bf16: hh + hl + lh)
        const s16x8 t0h = *(const s16x8*)(frags + l*16);
        const s16x8 t1h = *(const s16x8*)(frags + 1024 + l*16);
        const s16x8 t0l = *(const s16x8*)(frags + 2048 + l*16);
        const s16x8 t1l = *(const s16x8*)(frags + 3072 + l*16);
        const float4 b0 = *(const float4*)(theta_b + 4*kb);
        const float4 b1 = *(const float4*)(theta_b + 16 + 4*kb);
        f32x4v T0; T0[0]=b0.x; T0[1]=b0.y; T0[2]=b0.z; T0[3]=b0.w;
        f32x4v T1; T1[0]=b1.x; T1[1]=b1.y; T1[2]=b1.z; T1[3]=b1.w;
        T0 = MFMA16(t0h, bxh, T0, 0, 0, 0);
        T0 = MFMA16(t0h, bxl, T0, 0, 0, 0);
        T0 = MFMA16(t0l, bxh, T0, 0, 0, 0);
        T1 = MFMA16(t1h, bxh, T1, 0, 0, 0);
        T1 = MFMA16(t1h, bxl, T1, 0, 0, 0);
        T1 = MFMA16(t1l, bxh, T1, 0, 0, 0);
        // P = phi*X + pb (split compute, hi store)
        const s16x8 p0h = *(const s16x8*)(frags + 4096 + l*16);
        const s16x8 p1h = *(const s16x8*)(frags + 4096 + 1024 + l*16);
        const s16x8 p0l = *(const s16x8*)(frags + 4096 + 2048 + l*16);
        const s16x8 p1l = *(const s16x8*)(frags + 4096 + 3072 + l*16);
        const float4 c0 = *(const float4*)(phi_b + 4*kb);
        const float4 c1 = *(const float4*)(phi_b + 16 + 4*kb);
        f32x4v P0; P0[0]=c0.x; P0[1]=c0.y; P0[2]=c0.z; P0[3]=c0.w;
        f32x4v P1; P1[0]=c1.x; P1[1]=c1.y; P1[2]=c1.z; P1[3]=c1.w;
        P0 = MFMA16(p0h, bxh, P0, 0, 0, 0);
        P0 = MFMA16(p0h, bxl, P0, 0, 0, 0);
        P0 = MFMA16(p0l, bxh, P0, 0, 0, 0);
        P1 = MFMA16(p1h, bxh, P1, 0, 0, 0);
        P1 = MFMA16(p1h, bxl, P1, 0, 0, 0);
        P1 = MFMA16(p1l, bxh, P1, 0, 0, 0);
        // store P hi at [y=zr][p], p = 8kb+4mt+r -> uint64 per mt at byte 16kb+8mt
        union { uint32_t u[2]; uint64_t q; } w;
        w.u[0] = pkbf(P0[0], P0[1]); w.u[1] = pkbf(P0[2], P0[3]);
        *(uint64_t*)(lds + OP + zr*72 + 16*kb) = w.q;
        w.u[0] = pkbf(P1[0], P1[1]); w.u[1] = pkbf(P1[2], P1[3]);
        *(uint64_t*)(lds + OP + zr*72 + 16*kb + 8) = w.q;
        // T -> hi/lo B-frags in-register (slot j = 4mt+r)
        uint16_t h[8];
        #pragma unroll
        for (int r = 0; r < 4; ++r) { h[r] = bfh(T0[r]); h[4+r] = bfh(T1[r]); }
        union { uint32_t u[4]; s16x8 s; } H, L;
        H.u[0] = pk2u(h[0], h[1]); H.u[1] = pk2u(h[2], h[3]);
        H.u[2] = pk2u(h[4], h[5]); H.u[3] = pk2u(h[6], h[7]);
        L.u[0] = pkbf(T0[0]-bf2f(h[0]), T0[1]-bf2f(h[1]));
        L.u[1] = pkbf(T0[2]-bf2f(h[2]), T0[3]-bf2f(h[3]));
        L.u[2] = pkbf(T1[0]-bf2f(h[4]), T1[1]-bf2f(h[5]));
        L.u[3] = pkbf(T1[2]-bf2f(h[6]), T1[3]-bf2f(h[7]));
        bth = H.s; btl = L.s;
    }
    __syncthreads();   // B2 (P complete)

    // ===== phase 2a: F' = P^T * (T_hi + T_lo), D[y=16yt+4kb+r][z=zr] =====
    f32x4v Fq[4];
    #pragma unroll
    for (int yt = 0; yt < 4; ++yt) {
        const s16x8 pah = rd8(lds + OP + (16*yt + l15)*72 + 16*kb);
        f32x4v zz; zz[0]=0.f; zz[1]=0.f; zz[2]=0.f; zz[3]=0.f;
        zz = MFMA16(pah, bth, zz, 0, 0, 0);
        zz = MFMA16(pah, btl, zz, 0, 0, 0);
        Fq[yt] = zz;
    }

    // ===== phase 2b: softmax over y (in-register), pack A' PV-B-frags =====
    s16x8 apk[2];
    {
        float mx = -3.4e38f;
        #pragma unroll
        for (int yt = 0; yt < 4; ++yt)
            #pragma unroll
            for (int r = 0; r < 4; ++r) mx = fmaxf(mx, Fq[yt][r]);
        mx = fmaxf(mx, __shfl_xor(mx, 16));
        mx = fmaxf(mx, __shfl_xor(mx, 32));
        float p[4][4]; float sum = 0.f;
        #pragma unroll
        for (int yt = 0; yt < 4; ++yt)
            #pragma unroll
            for (int r = 0; r < 4; ++r) { p[yt][r] = __expf(Fq[yt][r] - mx); sum += p[yt][r]; }
        sum += __shfl_xor(sum, 16);
        sum += __shfl_xor(sum, 32);
        const float inv = 1.0f / sum;
        #pragma unroll
        for (int ks = 0; ks < 2; ++ks) {
            union { uint32_t u[4]; s16x8 s; } A;
            A.u[0] = pkbf(p[2*ks][0]*inv,   p[2*ks][1]*inv);
            A.u[1] = pkbf(p[2*ks][2]*inv,   p[2*ks][3]*inv);
            A.u[2] = pkbf(p[2*ks+1][0]*inv, p[2*ks+1][1]*inv);
            A.u[3] = pkbf(p[2*ks+1][2]*inv, p[2*ks+1][3]*inv);
            apk[ks] = A.s;
        }
    }

    // ===== phase 3: Y = G * A'^T, residual(+mask), R -> bf16 frags in regs =====
    s16x8 brf[2];   // R as W-B-frags per mt' (slot j = 4mt'+r ... packed per mt')
    {
        f32x4v Yq[2];
        #pragma unroll
        for (int r = 0; r < 4; ++r) { Yq[0][r] = 0.f; Yq[1][r] = 0.f; }
        #pragma unroll
        for (int ks = 0; ks < 2; ++ks) {
            #pragma unroll
            for (int mt = 0; mt < 2; ++mt) {
                const s16x8 gA = rd8(lds + OG + (16*mt + l15)*136 + 64*ks + 16*kb);
                Yq[mt] = MFMA16(gA, apk[ks], Yq[mt], 0, 0, 0);
            }
        }
        const bool msk = spacings[b*3 + 2] <= 1.5f;
        union { uint32_t u[4]; s16x8 s; } R;
        #pragma unroll
        for (int mt = 0; mt < 2; ++mt) {
            const uint64_t xh = *(const uint64_t*)(lds + OXH + zr*136 + (16*mt + 4*kb)*2);
            float rv[4];
            #pragma unroll
            for (int r = 0; r < 4; ++r) {
                const float xr = bf2f((uint16_t)(xh >> (16*r)));
                rv[r] = msk ? (Yq[mt][r] + xr) : xr;
            }
            R.u[2*mt]   = pkbf(rv[0], rv[1]);
            R.u[2*mt+1] = pkbf(rv[2], rv[3]);
        }
        brf[0] = R.s;   // single frag covers k=c 0..31 (slots j=4mt+r)
    }
    __syncthreads();   // B3 (all P/G/X reads done -> Ot may overlay OP+OG)

    // ===== phase 4: O = W * R + wb -> Ot f32 [z][33] stride 132 =====
    {
        #pragma unroll
        for (int mt = 0; mt < 2; ++mt) {
            const s16x8 aW = *(const s16x8*)(frags + 8192 + (mt*64 + l)*16);
            const float4 wb4 = *(const float4*)(Wb + 16*mt + 4*kb);
            f32x4v acc; acc[0]=wb4.x; acc[1]=wb4.y; acc[2]=wb4.z; acc[3]=wb4.w;
            acc = MFMA16(aW, brf[0], acc, 0, 0, 0);
            #pragma unroll
            for (int r = 0; r < 4; ++r)
                *(float*)(lds + OO + zr*132 + (16*mt + 4*kb + r)*4) = acc[r];
        }
    }
    __syncthreads();   // B4

    // ===== phase 5: coalesced store + BN partials (butterfly) =====
    #pragma unroll
    for (int k = 0; k < 8; ++k) {
        const int o = wv + 4*k;
        const float v = *(const float*)(lds + OO + l*132 + o*4);
        out[base + (long)o*CHS + l] = v;
        float s1 = v, s2 = v*v;
        #pragma unroll
        for (int off = 32; off >= 1; off >>= 1) {
            s1 += __shfl_xor(s1, off);
            s2 += __shfl_xor(s2, off);
        }
        if (l == 0) {
            part[row*64 + o]      = s1;
            part[row*64 + 32 + o] = s2;
        }
    }
}

// stage 2a: 256 blocks reduce 72 rows each
__global__ __launch_bounds__(256) void k2a(const float* __restrict__ part,
                                           float* __restrict__ part2)
{
    __shared__ float red[4][64];
    const int t = threadIdx.x, lane = t & 63, grp = t >> 6;
    const int p = blockIdx.x;
    float s = 0.f;
    for (int k = 0; k < 18; ++k) s += part[(p*72 + grp + 4*k)*64 + lane];
    red[grp][lane] = s;
    __syncthreads();
    if (t < 64) part2[p*64 + t] = red[0][t] + red[1][t] + red[2][t] + red[3][t];
}

// stage 2b: final reduce + BN scale/shift
__global__ __launch_bounds__(256) void k2b(const float* __restrict__ part2,
    const float* __restrict__ gamma, const float* __restrict__ beta,
    float* __restrict__ sc)
{
    __shared__ float red[4][64];
    __shared__ float tot[64];
    const int t = threadIdx.x, lane = t & 63, grp = t >> 6;
    float s = 0.f;
    for (int k = 0; k < 64; ++k) s += part2[(grp + 4*k)*64 + lane];
    red[grp][lane] = s;
    __syncthreads();
    if (t < 64) tot[t] = red[0][t] + red[1][t] + red[2][t] + red[3][t];
    __syncthreads();
    if (t < 32) {
        const float mean = tot[t] / NRED;
        const float var  = tot[32+t] / NRED - mean*mean;
        const float rstd = rsqrtf(var + 1e-5f);
        const float scale = gamma[t] * rstd;
        sc[t]    = scale;
        sc[32+t] = fmaf(-mean, scale, beta[t]);
    }
}

// stage 3: in-place affine normalize of d_out
__global__ __launch_bounds__(256) void k3_norm(float* __restrict__ out,
                                               const float* __restrict__ sc)
{
    __shared__ float s[64];
    if (threadIdx.x < 64) s[threadIdx.x] = sc[threadIdx.x];
    __syncthreads();
    const int total4 = 2*32*CHS/4;
    const int Q = CHS/4;
    for (int i = blockIdx.x*256 + threadIdx.x; i < total4; i += gridDim.x*256) {
        float4 v = ((const float4*)out)[i];
        const int c = (i / Q) & 31;
        const float scale = s[c], shift = s[32+c];
        v.x = fmaf(v.x, scale, shift);
        v.y = fmaf(v.y, scale, shift);
        v.z = fmaf(v.z, scale, shift);
        v.w = fmaf(v.w, scale, shift);
        ((float4*)out)[i] = v;
    }
}

extern "C" void kernel_launch(void* const* d_in, const int* in_sizes, int n_in,
                              void* d_out, int out_size, void* d_ws, size_t ws_size,
                              hipStream_t stream) {
    const float* x        = (const float*)d_in[0];
    const float* spacings = (const float*)d_in[1];
    const float* theta_w  = (const float*)d_in[2];
    const float* theta_b  = (const float*)d_in[3];
    const float* phi_w    = (const float*)d_in[4];
    const float* phi_b    = (const float*)d_in[5];
    const float* g_w      = (const float*)d_in[6];
    const float* g_b      = (const float*)d_in[7];
    const float* Ww       = (const float*)d_in[8];
    const float* Wb       = (const float*)d_in[9];
    const float* gamma    = (const float*)d_in[10];
    const float* beta     = (const float*)d_in[11];
    float* out   = (float*)d_out;
    char*  frags = (char*)d_ws;                         // WSFRAG bytes
    float* part  = (float*)((char*)d_ws + WSFRAG);      // ROWS*64 floats
    float* part2 = part + ROWS*64;                      // 256*64 floats
    float* sc    = part2 + 256*64;                      // 64 floats

    hipLaunchKernelGGL(k0_frag, dim3(1), dim3(256), 0, stream, theta_w, phi_w, Ww, frags);
    hipLaunchKernelGGL(k1_row, dim3(ROWS), dim3(256), 0, stream,
                       x, spacings, theta_b, phi_b, g_w, g_b, Wb, frags, out, part);
    hipLaunchKernelGGL(k2a, dim3(256), dim3(256), 0, stream, part, part2);
    hipLaunchKernelGGL(k2b, dim3(1), dim3(256), 0, stream, part2, gamma, beta, sc);
    hipLaunchKernelGGL(k3_norm, dim3(4096), dim3(256), 0, stream, out, sc);
}

// Round 10
// 179.810 us; speedup vs baseline: 1.1200x; 1.0827x over previous
//
#include <hip/hip_runtime.h>
#include <stdint.h>

#define CHS 589824           // W*H*Z
#define ROWS 18432           // B*W*H
#define WHn 9216             // W*H
#define NRED 1179648.0f      // B*W*H*Z
#define LOG2E 1.4426950408889634f

typedef short s16x8 __attribute__((ext_vector_type(8)));
typedef float f32x4v __attribute__((ext_vector_type(4)));

#define MFMA16 __builtin_amdgcn_mfma_f32_16x16x32_bf16

// ws layout (bytes): [0,10240) weight frags ; then part/part2/sc (f32)
//   frags: thetaH 0, thetaL 2048, phiH 4096, phiL 6144, W 8192 (c-permuted)
//   theta frags pre-scaled by LOG2E (exp2 softmax trick)
#define WSFRAG 10240

// LDS regions (one block = one (b,w,h) row)
#define OXH 0        // X bf16 [z=64][ hi c:32 (64B) | lo c:32 (64B) ] stride 136 (8704)
#define OP  8704     // P_hi bf16 [y=64][p:36] stride 72 (4608)  p = 8kb+4mt+r slot order
#define OG  13312    // G bf16 [c=32][p_G:68] stride 136 (4352)  p_G = y-permuted slot order
#define LDSZ 17664   // 8 blocks/CU
// overlays:
#define OO  OP       // Ot f32 [z=64][o:33] stride 132 (8448 <= 8960), after B3
#define OSC OXH      // BN scratch f32 [wv][plane][32] = 1KB, after B3 (X dead)

static __device__ __forceinline__ uint16_t bfh(float v) {
    union { __bf16 h; uint16_t u; } c; c.h = (__bf16)v; return c.u;
}
static __device__ __forceinline__ float bf2f(uint16_t u) {
    union { uint32_t x; float f; } c; c.x = (uint32_t)u << 16; return c.f;
}
static __device__ __forceinline__ uint32_t pk2u(uint16_t a, uint16_t b) {
    return (uint32_t)a | ((uint32_t)b << 16);
}
static __device__ __forceinline__ uint32_t pkbf(float a, float b) {
    return pk2u(bfh(a), bfh(b));
}
static __device__ __forceinline__ float ex2(float x) {
    float r;
    asm("v_exp_f32 %0, %1" : "=v"(r) : "v"(x));
    return r;
}
// 16B from 8B-aligned LDS as two b64s
static __device__ __forceinline__ s16x8 rd8(const char* p) {
    union { uint64_t q[2]; s16x8 s; } v;
    v.q[0] = *(const uint64_t*)p;
    v.q[1] = *(const uint64_t*)(p + 8);
    return v.s;
}

// identity-k hi+lo A-frags of row-major [32][32] f32 weights, optional pre-scale
static __device__ __forceinline__ void wfrag2(const float* __restrict__ Wp, int mt, int l15, int kb,
                                              float sc, s16x8& hi, s16x8& lo) {
    const float* p = Wp + (l15 + 16*mt)*32 + 8*kb;
    const float4 f0 = *(const float4*)p;
    const float4 f1 = *(const float4*)(p + 4);
    float f[8] = {f0.x*sc, f0.y*sc, f0.z*sc, f0.w*sc, f1.x*sc, f1.y*sc, f1.z*sc, f1.w*sc};
    union { uint32_t u[4]; s16x8 v; } rh, rl;
    #pragma unroll
    for (int i = 0; i < 4; ++i) {
        const uint16_t h0 = bfh(f[2*i]), h1 = bfh(f[2*i+1]);
        rh.u[i] = pk2u(h0, h1);
        rl.u[i] = pk2u(bfh(f[2*i] - bf2f(h0)), bfh(f[2*i+1] - bf2f(h1)));
    }
    hi = rh.v; lo = rl.v;
}
// c-permuted A-frag for W (slot j <-> c = 16*(j>>2) + 4*kb + (j&3))
static __device__ __forceinline__ s16x8 wfragW(const float* __restrict__ Wp, int mt, int l15, int kb) {
    const float* p = Wp + (l15 + 16*mt)*32;
    const float4 f0 = *(const float4*)(p + 4*kb);
    const float4 f1 = *(const float4*)(p + 16 + 4*kb);
    union { uint32_t u[4]; s16x8 v; } r;
    r.u[0] = pkbf(f0.x, f0.y); r.u[1] = pkbf(f0.z, f0.w);
    r.u[2] = pkbf(f1.x, f1.y); r.u[3] = pkbf(f1.z, f1.w);
    return r.v;
}

// k0: one block, precompute weight fragments into ws (theta scaled by LOG2E)
__global__ __launch_bounds__(256) void k0_frag(
    const float* __restrict__ theta_w, const float* __restrict__ phi_w,
    const float* __restrict__ Ww, char* __restrict__ ws)
{
    const int tid = threadIdx.x;
    const int m = tid >> 7;            // 0 = theta, 1 = phi
    const int r = tid & 127;
    const int mt = r >> 6, l = r & 63;
    s16x8 hi, lo;
    wfrag2(m ? phi_w : theta_w, mt, l & 15, l >> 4, m ? 1.0f : LOG2E, hi, lo);
    *(s16x8*)(ws + m*4096 + (mt*64 + l)*16)        = hi;
    *(s16x8*)(ws + m*4096 + 2048 + (mt*64 + l)*16) = lo;
    if (tid < 128) {
        const int mtw = tid >> 6, lw = tid & 63;
        *(s16x8*)(ws + 8192 + (mtw*64 + lw)*16) = wfragW(Ww, mtw, lw & 15, lw >> 4);
    }
}

__global__ __launch_bounds__(256, 8) void k1_row(
    const float* __restrict__ x, const float* __restrict__ spacings,
    const float* __restrict__ theta_b, const float* __restrict__ phi_b,
    const float* __restrict__ g_w, const float* __restrict__ g_b,
    const float* __restrict__ Wb, const char* __restrict__ frags,
    float* __restrict__ out, float* __restrict__ part)
{
    __shared__ __align__(16) char lds[LDSZ];
    const int t = threadIdx.x;
    const int wv = t >> 6, l = t & 63;
    const int l15 = l & 15, kb = l >> 4;
    const int row = blockIdx.x;
    const int b = row / WHn, wh = row - b*WHn;
    const long base = (long)b*32*CHS + (long)wh*64;
    const int zr = 16*wv + l15;   // this wave's z (= y) tile column

    // ===== phase 0: load x col z=l (8 channels), write X hi|lo planes, G via shfl =====
    float xv[8];
    #pragma unroll
    for (int j = 0; j < 8; ++j) xv[j] = x[base + (long)(8*wv + j)*CHS + l];
    #pragma unroll
    for (int j = 0; j < 4; ++j) {
        const uint16_t h0 = bfh(xv[2*j]), h1 = bfh(xv[2*j+1]);
        *(uint32_t*)(lds + OXH + l*136 + (8*wv + 2*j)*2)      = pk2u(h0, h1);
        *(uint32_t*)(lds + OXH + l*136 + 64 + (8*wv + 2*j)*2) =
            pk2u(bfh(xv[2*j] - bf2f(h0)), bfh(xv[2*j+1] - bf2f(h1)));
    }
    // G store position: p_G(y=l) = 32*(l>>5) + 8*((l>>2)&3) + 4*((l>>4)&1) + (l&3)
    const int pG = 32*(l >> 5) + 8*((l >> 2) & 3) + 4*((l >> 4) & 1) + (l & 3);
    #pragma unroll
    for (int j = 0; j < 8; ++j) {
        const int c = 8*wv + j;
        float xm = __shfl_up(xv[j], 1);   if (l == 0)  xm = 0.f;
        float xp = __shfl_down(xv[j], 1); if (l == 63) xp = 0.f;
        const float g = g_w[3*c]*xm + g_w[3*c+1]*xv[j] + g_w[3*c+2]*xp + g_b[c];
        *(uint16_t*)(lds + OG + c*136 + 2*pG) = bfh(g);
    }
    __syncthreads();   // B1

    // ===== phase 1: own z-tile T (kept in regs, log2e-scaled) and P (hi -> LDS) =====
    s16x8 bth, btl;   // T as F'-B-frags (slot j = 4*mt + r), hi+lo
    {
        const s16x8 bxh = rd8(lds + OXH + zr*136 + 16*kb);
        const s16x8 bxl = rd8(lds + OXH + zr*136 + 64 + 16*kb);
        // T = (LOG2E*theta)*X + LOG2E*tb (split bf16: hh + hl + lh)
        const s16x8 t0h = *(const s16x8*)(frags + l*16);
        const s16x8 t1h = *(const s16x8*)(frags + 1024 + l*16);
        const s16x8 t0l = *(const s16x8*)(frags + 2048 + l*16);
        const s16x8 t1l = *(const s16x8*)(frags + 3072 + l*16);
        const float4 b0 = *(const float4*)(theta_b + 4*kb);
        const float4 b1 = *(const float4*)(theta_b + 16 + 4*kb);
        f32x4v T0; T0[0]=b0.x*LOG2E; T0[1]=b0.y*LOG2E; T0[2]=b0.z*LOG2E; T0[3]=b0.w*LOG2E;
        f32x4v T1; T1[0]=b1.x*LOG2E; T1[1]=b1.y*LOG2E; T1[2]=b1.z*LOG2E; T1[3]=b1.w*LOG2E;
        T0 = MFMA16(t0h, bxh, T0, 0, 0, 0);
        T0 = MFMA16(t0h, bxl, T0, 0, 0, 0);
        T0 = MFMA16(t0l, bxh, T0, 0, 0, 0);
        T1 = MFMA16(t1h, bxh, T1, 0, 0, 0);
        T1 = MFMA16(t1h, bxl, T1, 0, 0, 0);
        T1 = MFMA16(t1l, bxh, T1, 0, 0, 0);
        // P = phi*X + pb (split compute, hi store)
        const s16x8 p0h = *(const s16x8*)(frags + 4096 + l*16);
        const s16x8 p1h = *(const s16x8*)(frags + 4096 + 1024 + l*16);
        const s16x8 p0l = *(const s16x8*)(frags + 4096 + 2048 + l*16);
        const s16x8 p1l = *(const s16x8*)(frags + 4096 + 3072 + l*16);
        const float4 c0 = *(const float4*)(phi_b + 4*kb);
        const float4 c1 = *(const float4*)(phi_b + 16 + 4*kb);
        f32x4v P0; P0[0]=c0.x; P0[1]=c0.y; P0[2]=c0.z; P0[3]=c0.w;
        f32x4v P1; P1[0]=c1.x; P1[1]=c1.y; P1[2]=c1.z; P1[3]=c1.w;
        P0 = MFMA16(p0h, bxh, P0, 0, 0, 0);
        P0 = MFMA16(p0h, bxl, P0, 0, 0, 0);
        P0 = MFMA16(p0l, bxh, P0, 0, 0, 0);
        P1 = MFMA16(p1h, bxh, P1, 0, 0, 0);
        P1 = MFMA16(p1h, bxl, P1, 0, 0, 0);
        P1 = MFMA16(p1l, bxh, P1, 0, 0, 0);
        // store P hi at [y=zr][p], p = 8kb+4mt+r
        union { uint32_t u[2]; uint64_t q; } w;
        w.u[0] = pkbf(P0[0], P0[1]); w.u[1] = pkbf(P0[2], P0[3]);
        *(uint64_t*)(lds + OP + zr*72 + 16*kb) = w.q;
        w.u[0] = pkbf(P1[0], P1[1]); w.u[1] = pkbf(P1[2], P1[3]);
        *(uint64_t*)(lds + OP + zr*72 + 16*kb + 8) = w.q;
        // T -> hi/lo B-frags in-register (slot j = 4mt+r)
        uint16_t h[8];
        #pragma unroll
        for (int r = 0; r < 4; ++r) { h[r] = bfh(T0[r]); h[4+r] = bfh(T1[r]); }
        union { uint32_t u[4]; s16x8 s; } H, L;
        H.u[0] = pk2u(h[0], h[1]); H.u[1] = pk2u(h[2], h[3]);
        H.u[2] = pk2u(h[4], h[5]); H.u[3] = pk2u(h[6], h[7]);
        L.u[0] = pkbf(T0[0]-bf2f(h[0]), T0[1]-bf2f(h[1]));
        L.u[1] = pkbf(T0[2]-bf2f(h[2]), T0[3]-bf2f(h[3]));
        L.u[2] = pkbf(T1[0]-bf2f(h[4]), T1[1]-bf2f(h[5]));
        L.u[3] = pkbf(T1[2]-bf2f(h[6]), T1[3]-bf2f(h[7]));
        bth = H.s; btl = L.s;
    }
    __syncthreads();   // B2 (P complete)

    // ===== phase 2a: F' = P^T * (T_hi + T_lo), D[y=16yt+4kb+r][z=zr] =====
    f32x4v Fq[4];
    #pragma unroll
    for (int yt = 0; yt < 4; ++yt) {
        const s16x8 pah = rd8(lds + OP + (16*yt + l15)*72 + 16*kb);
        f32x4v zz; zz[0]=0.f; zz[1]=0.f; zz[2]=0.f; zz[3]=0.f;
        zz = MFMA16(pah, bth, zz, 0, 0, 0);
        zz = MFMA16(pah, btl, zz, 0, 0, 0);
        Fq[yt] = zz;
    }

    // ===== phase 2b: softmax over y via exp2 (unnormalized), pack A' PV-B-frags =====
    s16x8 apk[2];
    float inv;
    {
        float mx = -3.4e38f;
        #pragma unroll
        for (int yt = 0; yt < 4; ++yt)
            #pragma unroll
            for (int r = 0; r < 4; ++r) mx = fmaxf(mx, Fq[yt][r]);
        mx = fmaxf(mx, __shfl_xor(mx, 16));
        mx = fmaxf(mx, __shfl_xor(mx, 32));
        float p[4][4]; float sum = 0.f;
        #pragma unroll
        for (int yt = 0; yt < 4; ++yt)
            #pragma unroll
            for (int r = 0; r < 4; ++r) { p[yt][r] = ex2(Fq[yt][r] - mx); sum += p[yt][r]; }
        sum += __shfl_xor(sum, 16);
        sum += __shfl_xor(sum, 32);
        inv = 1.0f / sum;
        #pragma unroll
        for (int ks = 0; ks < 2; ++ks) {
            union { uint32_t u[4]; s16x8 s; } A;
            A.u[0] = pkbf(p[2*ks][0],   p[2*ks][1]);
            A.u[1] = pkbf(p[2*ks][2],   p[2*ks][3]);
            A.u[2] = pkbf(p[2*ks+1][0], p[2*ks+1][1]);
            A.u[3] = pkbf(p[2*ks+1][2], p[2*ks+1][3]);
            apk[ks] = A.s;
        }
    }

    // ===== phase 3: Y_un = G * A'^T, Y = Y_un*inv (+x, mask), R -> bf16 frag =====
    s16x8 brf;
    {
        f32x4v Yq[2];
        #pragma unroll
        for (int r = 0; r < 4; ++r) { Yq[0][r] = 0.f; Yq[1][r] = 0.f; }
        #pragma unroll
        for (int ks = 0; ks < 2; ++ks) {
            #pragma unroll
            for (int mt = 0; mt < 2; ++mt) {
                const s16x8 gA = rd8(lds + OG + (16*mt + l15)*136 + 64*ks + 16*kb);
                Yq[mt] = MFMA16(gA, apk[ks], Yq[mt], 0, 0, 0);
            }
        }
        const bool msk = spacings[b*3 + 2] <= 1.5f;
        union { uint32_t u[4]; s16x8 s; } R;
        #pragma unroll
        for (int mt = 0; mt < 2; ++mt) {
            const uint64_t xh = *(const uint64_t*)(lds + OXH + zr*136 + (16*mt + 4*kb)*2);
            float rv[4];
            #pragma unroll
            for (int r = 0; r < 4; ++r) {
                const float xr = bf2f((uint16_t)(xh >> (16*r)));
                rv[r] = msk ? fmaf(Yq[mt][r], inv, xr) : xr;
            }
            R.u[2*mt]   = pkbf(rv[0], rv[1]);
            R.u[2*mt+1] = pkbf(rv[2], rv[3]);
        }
        brf = R.s;
    }
    __syncthreads();   // B3 (all P/G/X reads done -> Ot overlays OP+OG, scratch at OXH)

    // ===== phase 4: O = W * R + wb -> Ot f32 [z][33]; BN butterfly from regs =====
    {
        f32x4v accs[2];
        #pragma unroll
        for (int mt = 0; mt < 2; ++mt) {
            const s16x8 aW = *(const s16x8*)(frags + 8192 + (mt*64 + l)*16);
            const float4 wb4 = *(const float4*)(Wb + 16*mt + 4*kb);
            f32x4v acc; acc[0]=wb4.x; acc[1]=wb4.y; acc[2]=wb4.z; acc[3]=wb4.w;
            acc = MFMA16(aW, brf, acc, 0, 0, 0);
            accs[mt] = acc;
            #pragma unroll
            for (int r = 0; r < 4; ++r)
                *(float*)(lds + OO + zr*132 + (16*mt + 4*kb + r)*4) = acc[r];
        }
        // BN partial sums over z-tile (16 l15 lanes), s1 then s2 (VGPR-friendly)
        float bs[8];
        #pragma unroll
        for (int mt = 0; mt < 2; ++mt)
            #pragma unroll
            for (int r = 0; r < 4; ++r) bs[4*mt+r] = accs[mt][r];
        #pragma unroll
        for (int off = 1; off < 16; off <<= 1)
            #pragma unroll
            for (int i = 0; i < 8; ++i) bs[i] += __shfl_xor(bs[i], off);
        if (l15 == 0) {
            #pragma unroll
            for (int mt = 0; mt < 2; ++mt) {
                union { float f[2]; uint64_t q; } w0, w1;
                w0.f[0] = bs[4*mt]; w0.f[1] = bs[4*mt+1];
                w1.f[0] = bs[4*mt+2]; w1.f[1] = bs[4*mt+3];
                *(uint64_t*)(lds + OSC + wv*256 + (16*mt + 4*kb)*4)     = w0.q;
                *(uint64_t*)(lds + OSC + wv*256 + (16*mt + 4*kb)*4 + 8) = w1.q;
            }
        }
        #pragma unroll
        for (int mt = 0; mt < 2; ++mt)
            #pragma unroll
            for (int r = 0; r < 4; ++r) { const float v = accs[mt][r]; bs[4*mt+r] = v*v; }
        #pragma unroll
        for (int off = 1; off < 16; off <<= 1)
            #pragma unroll
            for (int i = 0; i < 8; ++i) bs[i] += __shfl_xor(bs[i], off);
        if (l15 == 0) {
            #pragma unroll
            for (int mt = 0; mt < 2; ++mt) {
                union { float f[2]; uint64_t q; } w0, w1;
                w0.f[0] = bs[4*mt]; w0.f[1] = bs[4*mt+1];
                w1.f[0] = bs[4*mt+2]; w1.f[1] = bs[4*mt+3];
                *(uint64_t*)(lds + OSC + wv*256 + 128 + (16*mt + 4*kb)*4)     = w0.q;
                *(uint64_t*)(lds + OSC + wv*256 + 128 + (16*mt + 4*kb)*4 + 8) = w1.q;
            }
        }
    }
    __syncthreads();   // B4

    // ===== phase 5: coalesced store + cross-wave BN reduce =====
    #pragma unroll
    for (int k = 0; k < 8; ++k) {
        const int o = wv + 4*k;
        out[base + (long)o*CHS + l] = *(const float*)(lds + OO + l*132 + o*4);
    }
    if (t < 64) {
        const int pl = t >> 5, o = t & 31;
        float s = 0.f;
        #pragma unroll
        for (int w = 0; w < 4; ++w)
            s += *(const float*)(lds + OSC + w*256 + pl*128 + o*4);
        part[row*64 + t] = s;
    }
}

// stage 2a: 256 blocks reduce 72 rows each
__global__ __launch_bounds__(256) void k2a(const float* __restrict__ part,
                                           float* __restrict__ part2)
{
    __shared__ float red[4][64];
    const int t = threadIdx.x, lane = t & 63, grp = t >> 6;
    const int p = blockIdx.x;
    float s = 0.f;
    for (int k = 0; k < 18; ++k) s += part[(p*72 + grp + 4*k)*64 + lane];
    red[grp][lane] = s;
    __syncthreads();
    if (t < 64) part2[p*64 + t] = red[0][t] + red[1][t] + red[2][t] + red[3][t];
}

// stage 2b: final reduce + BN scale/shift
__global__ __launch_bounds__(256) void k2b(const float* __restrict__ part2,
    const float* __restrict__ gamma, const float* __restrict__ beta,
    float* __restrict__ sc)
{
    __shared__ float red[4][64];
    __shared__ float tot[64];
    const int t = threadIdx.x, lane = t & 63, grp = t >> 6;
    float s = 0.f;
    for (int k = 0; k < 64; ++k) s += part2[(grp + 4*k)*64 + lane];
    red[grp][lane] = s;
    __syncthreads();
    if (t < 64) tot[t] = red[0][t] + red[1][t] + red[2][t] + red[3][t];
    __syncthreads();
    if (t < 32) {
        const float mean = tot[t] / NRED;
        const float var  = tot[32+t] / NRED - mean*mean;
        const float rstd = rsqrtf(var + 1e-5f);
        const float scale = gamma[t] * rstd;
        sc[t]    = scale;
        sc[32+t] = fmaf(-mean, scale, beta[t]);
    }
}

// stage 3: in-place affine normalize of d_out
__global__ __launch_bounds__(256) void k3_norm(float* __restrict__ out,
                                               const float* __restrict__ sc)
{
    __shared__ float s[64];
    if (threadIdx.x < 64) s[threadIdx.x] = sc[threadIdx.x];
    __syncthreads();
    const int total4 = 2*32*CHS/4;
    const int Q = CHS/4;
    for (int i = blockIdx.x*256 + threadIdx.x; i < total4; i += gridDim.x*256) {
        float4 v = ((const float4*)out)[i];
        const int c = (i / Q) & 31;
        const float scale = s[c], shift = s[32+c];
        v.x = fmaf(v.x, scale, shift);
        v.y = fmaf(v.y, scale, shift);
        v.z = fmaf(v.z, scale, shift);
        v.w = fmaf(v.w, scale, shift);
        ((float4*)out)[i] = v;
    }
}

extern "C" void kernel_launch(void* const* d_in, const int* in_sizes, int n_in,
                              void* d_out, int out_size, void* d_ws, size_t ws_size,
                              hipStream_t stream) {
    const float* x        = (const float*)d_in[0];
    const float* spacings = (const float*)d_in[1];
    const float* theta_w  = (const float*)d_in[2];
    const float* theta_b  = (const float*)d_in[3];
    const float* phi_w    = (const float*)d_in[4];
    const float* phi_b    = (const float*)d_in[5];
    const float* g_w      = (const float*)d_in[6];
    const float* g_b      = (const float*)d_in[7];
    const float* Ww       = (const float*)d_in[8];
    const float* Wb       = (const float*)d_in[9];
    const float* gamma    = (const float*)d_in[10];
    const float* beta     = (const float*)d_in[11];
    float* out   = (float*)d_out;
    char*  frags = (char*)d_ws;                         // WSFRAG bytes
    float* part  = (float*)((char*)d_ws + WSFRAG);      // ROWS*64 floats
    float* part2 = part + ROWS*64;                      // 256*64 floats
    float* sc    = part2 + 256*64;                      // 64 floats

    hipLaunchKernelGGL(k0_frag, dim3(1), dim3(256), 0, stream, theta_w, phi_w, Ww, frags);
    hipLaunchKernelGGL(k1_row, dim3(ROWS), dim3(256), 0, stream,
                       x, spacings, theta_b, phi_b, g_w, g_b, Wb, frags, out, part);
    hipLaunchKernelGGL(k2a, dim3(256), dim3(256), 0, stream, part, part2);
    hipLaunchKernelGGL(k2b, dim3(1), dim3(256), 0, stream, part2, gamma, beta, sc);
    hipLaunchKernelGGL(k3_norm, dim3(4096), dim3(256), 0, stream, out, sc);
}